// Round 19
// baseline (114.925 us; speedup 1.0000x reference)
//
#include <hip/hip_runtime.h>

// 3D trilinear warp (grid_sample, align_corners=True, border padding).
// image: (B=2, 1, 160, 192, 192) f32 | ddf: (B,3,D,H,W) f32 (dz,dy,dx voxels)
//
// Round-19: persistent blocks + cross-tile software pipeline (double-buffered
// bf16 LDS windows).
//  - Grid = 256 blocks = exactly 1/CU (perfect balance), 1024 threads.
//    Each block owns 9 tiles (2304 total), ordered zh-fastest so consecutive
//    windows share 20/32 z-slices (restage hits L2).
//  - Tile = 32(x) x 8(y) x 20(z); window = 32 slices [zlo-4, zlo+28) of a
//    52x23 region, stored as packed bf16 in u32 (R16-verified path).
//    TWO buffers (2 x 76.6 KB): compute tile t from buf[t&1] while the
//    staging loads for tile t+1 are in flight; commits (pack + u32 stores)
//    land into buf[t&1 ^ 1] after each compute half -- the loads get the
//    whole compute phase to cover HBM/L2 latency (T14 at tile scale).
//  - Full window ready before compute -> uz<=30 for all k (fewer misses).
//    Misses push {s,dx,dy,dz} into parity-indexed LDS queues; per-tile
//    epilogue gathers exact f32 from global (L2-hot). Queue overflow falls
//    back inline.
//  - XCD swizzle on block id; ddf for tile t+1 prefetched during tile t.

typedef float f32x4 __attribute__((ext_vector_type(4)));
typedef float f32x2 __attribute__((ext_vector_type(2)));

constexpr int D_ = 160, H_ = 192, W_ = 192;
constexpr int HW_ = H_ * W_;
constexpr int N_  = D_ * HW_;

constexpr int TX_ = 32, TY_ = 8, ZRUN_ = 20;
constexpr int XT_ = 6, YT_ = 24, ZH_ = 8;
constexpr int NBLK_ = 256;                  // 1 per CU
constexpr int TPB_  = 9;                    // tiles per block (6*24*8*2 / 256)

constexpr int RX_ = 52, RY_ = 23, NZ_ = 32;
constexpr int SLICE_ = RX_ * RY_;           // 1196 elements (even)
constexpr int HSL_ = SLICE_ / 2;            // 598 u32 per slice
constexpr int CPS_ = SLICE_ / 4;            // 299 chunks per slice
constexpr int CPR_ = RX_ / 4;               // 13 chunks per row
constexpr int LIM_ = NZ_ * SLICE_ - RX_ - 2;// 38218 max safe elem offset
constexpr int BUFW_ = NZ_ * HSL_ + 2;       // 19138 u32 (+pad for pair read)
constexpr int QCAP_ = 128;

__device__ __forceinline__ unsigned bfpack(float lo, float hi) {
    unsigned a = (__builtin_bit_cast(unsigned, lo) + 0x8000u) >> 16;
    unsigned b = (__builtin_bit_cast(unsigned, hi) + 0x8000u) & 0xFFFF0000u;
    return a | b;
}

__global__ __launch_bounds__(1024) void warp3d_kernel(
    const float* __restrict__ img,
    const float* __restrict__ ddf,
    float* __restrict__ out)
{
    __shared__ unsigned buf[2][BUFW_];      // 153,104 B
    __shared__ f32x4 qd[2][QCAP_];          // 4,096 B
    __shared__ int   qc[2];

    int bid = blockIdx.x;
    int swz = (bid & 7) * 32 + (bid >> 3);  // XCD-chunked, bijective (256%8==0)
    int base_idx = swz * TPB_;

    int tid = threadIdx.x;
    int xi = tid & 31;
    int yy = (tid >> 5) & 7;
    int zz = tid >> 8;                      // 0..3

    // tile decomposition: idx -> (tx,ty,zh,b), zh fastest
    auto decomp = [&](int idx, int& tx, int& ty, int& zh, int& b) {
        zh = idx & 7; int rest = idx >> 3;
        tx = rest % XT_; int r2 = rest / XT_;
        ty = r2 % YT_;  b = r2 / YT_;
    };

    // ---- tile 0 params ----
    int tx, ty, zh, b;
    decomp(base_idx, tx, ty, zh, b);
    int zlo = zh * ZRUN_, vz0 = zlo - 4;
    int rx = min(max(tx * TX_ - 8, 0), W_ - RX_);
    int ry = min(max(ty * TY_ - 7, 0), H_ - RY_);
    const float* im = img + (size_t)b * N_;
    const float* dp = ddf + (size_t)b * 3 * N_;
    float*       op = out + (size_t)b * N_;
    int x = tx * TX_ + xi;
    int y = ty * TY_ + yy;
    int s0 = ((zlo + zz) * H_ + y) * W_ + x;

    // ddf[0]
    float cdz[5], cdy[5], cdx[5];
#pragma unroll
    for (int k = 0; k < 5; ++k) {
        int s = s0 + k * 4 * HW_;
        cdz[k] = __builtin_nontemporal_load(dp + s);
        cdy[k] = __builtin_nontemporal_load(dp + N_ + s);
        cdx[k] = __builtin_nontemporal_load(dp + 2 * N_ + s);
    }

    if (tid < 2) qc[tid] = 0;

    // ---- prologue: stage window 0 into buf[0] (direct) ----
    {
        int pz0 = max(0, vz0), pz1 = min(D_, zlo + 28);
        int pcnt = (pz1 - pz0) * CPS_;
        for (int c = tid; c < pcnt; c += 1024) {
            int si = c / CPS_, rem = c - si * CPS_;
            int zs = pz0 + si;
            int row = rem / CPR_, col = rem - row * CPR_;
            f32x4 v = *(const f32x4*)(im + (zs * H_ + ry + row) * W_ + rx + col * 4);
            int p = (zs - vz0) * HSL_ + rem * 2;
            buf[0][p] = bfpack(v.x, v.y);
            buf[0][p + 1] = bfpack(v.z, v.w);
        }
    }
    __syncthreads();

    for (int t = 0; t < TPB_; ++t) {
        int par = t & 1;
        const unsigned* bR = buf[par];
        unsigned* bW = buf[par ^ 1];
        bool more = (t + 1 < TPB_);

        // ---- next-tile params ----
        int nzlo = 0, nvz0 = 0, nrx = 0, nry = 0, ns0 = 0, nx = 0, nyv = 0;
        const float* nim = im; const float* ndp = dp; float* nop = op;
        if (more) {
            int ntx, nty, nzh, nb;
            decomp(base_idx + t + 1, ntx, nty, nzh, nb);
            nzlo = nzh * ZRUN_; nvz0 = nzlo - 4;
            nrx = min(max(ntx * TX_ - 8, 0), W_ - RX_);
            nry = min(max(nty * TY_ - 7, 0), H_ - RY_);
            nim = img + (size_t)nb * N_;
            ndp = ddf + (size_t)nb * 3 * N_;
            nop = out + (size_t)nb * N_;
            nx = ntx * TX_ + xi; nyv = nty * TY_ + yy;
            ns0 = ((nzlo + zz) * H_ + nyv) * W_ + nx;
        }

        // ---- prefetch ddf[t+1] ----
        float ndz[5], ndy[5], ndxr[5];
        if (more) {
#pragma unroll
            for (int k = 0; k < 5; ++k) {
                int s = ns0 + k * 4 * HW_;
                ndz[k]  = __builtin_nontemporal_load(ndp + s);
                ndy[k]  = __builtin_nontemporal_load(ndp + N_ + s);
                ndxr[k] = __builtin_nontemporal_load(ndp + 2 * N_ + s);
            }
        }

        // ---- staging geometry for window t+1 ----
        int npz0 = 0, npcnt = 0;
        if (more) {
            npz0 = max(0, nvz0);
            npcnt = (min(D_, nzlo + 28) - npz0) * CPS_;
        }

#define ISSUE(J, SV, SP, SM)                                            \
        {                                                               \
            int c = tid + (J << 10);                                    \
            SM = more && (c < npcnt);                                   \
            int si = c / CPS_, rem = c - si * CPS_;                     \
            int zs = npz0 + si;                                         \
            SP = (zs - nvz0) * HSL_ + rem * 2;                          \
            if (SM) {                                                   \
                int row = rem / CPR_, col = rem - row * CPR_;           \
                SV = *(const f32x4*)(nim + (zs * H_ + nry + row) * W_ + nrx + col * 4); \
            }                                                           \
        }
#define COMMIT(SV, SP, SM)                                              \
        if (SM) { bW[SP] = bfpack(SV.x, SV.y); bW[SP + 1] = bfpack(SV.z, SV.w); }

        f32x4 sv0, sv1, sv2, sv3, sv4;
        int   sp0, sp1, sp2, sp3, sp4;
        bool  sm0, sm1, sm2, sm3, sm4;

        // volley 1: chunks tid + {0..4}*1024
        ISSUE(0, sv0, sp0, sm0)
        ISSUE(1, sv1, sp1, sm1)
        ISSUE(2, sv2, sp2, sm2)
        ISSUE(3, sv3, sp3, sm3)
        ISSUE(4, sv4, sp4, sm4)

        // bf16 pair read from current buffer
        auto ldpair = [&](int o, float& e0, float& e1) {
            int p = o >> 1;
            unsigned w0 = bR[p];
            unsigned w1 = bR[p + 1];
            bool odd = (o & 1) != 0;
            unsigned u0 = odd ? (w0 & 0xFFFF0000u) : (w0 << 16);
            unsigned u1 = odd ? (w1 << 16)         : (w0 & 0xFFFF0000u);
            e0 = __builtin_bit_cast(float, u0);
            e1 = __builtin_bit_cast(float, u1);
        };

        auto gglobal = [&](int vx, int vy, int vz,
                           float gdx, float gdy, float gdz) -> float {
            float ix = fminf(fmaxf((float)vx + gdx, 0.f), (float)(W_ - 1));
            float iy = fminf(fmaxf((float)vy + gdy, 0.f), (float)(H_ - 1));
            float iz = fminf(fmaxf((float)vz + gdz, 0.f), (float)(D_ - 1));
            int x0 = min((int)ix, W_ - 2);
            int y0 = min((int)iy, H_ - 2);
            int z0 = min((int)iz, D_ - 2);
            float wx = ix - (float)x0;
            float wy = iy - (float)y0;
            float wz = iz - (float)z0;
            const float* p = im + (z0 * HW_ + y0 * W_ + x0);
            f32x2 a = *(const f32x2*)(p);
            f32x2 c = *(const f32x2*)(p + W_);
            f32x2 e = *(const f32x2*)(p + HW_);
            f32x2 f = *(const f32x2*)(p + HW_ + W_);
            float c00 = a.x + (a.y - a.x) * wx;
            float c01 = c.x + (c.y - c.x) * wx;
            float c10 = e.x + (e.y - e.x) * wx;
            float c11 = f.x + (f.y - f.x) * wx;
            float c0 = c00 + (c01 - c00) * wy;
            float c1 = c10 + (c11 - c10) * wy;
            return c0 + (c1 - c0) * wz;
        };

        auto process = [&](int z, int s, float gdx, float gdy, float gdz) {
            float ix = fminf(fmaxf((float)x + gdx, 0.f), (float)(W_ - 1));
            float iy = fminf(fmaxf((float)y + gdy, 0.f), (float)(H_ - 1));
            float iz = fminf(fmaxf((float)z + gdz, 0.f), (float)(D_ - 1));

            int x0 = min((int)ix, W_ - 2);
            int y0 = min((int)iy, H_ - 2);
            int z0 = min((int)iz, D_ - 2);
            float wx = ix - (float)x0;
            float wy = iy - (float)y0;
            float wz = iz - (float)z0;

            int ux = x0 - rx, uy = y0 - ry, uz = z0 - vz0;
            bool in = ((unsigned)ux <= (unsigned)(RX_ - 2)) &
                      ((unsigned)uy <= (unsigned)(RY_ - 2)) &
                      ((unsigned)uz <= 30u);

            int o0 = uz * SLICE_ + uy * RX_ + ux;
            o0 = min(max(o0, 0), LIM_);
            int o1 = min(o0 + SLICE_, LIM_);

            float v000, v001, v010, v011, v100, v101, v110, v111;
            ldpair(o0,       v000, v001);
            ldpair(o0 + RX_, v010, v011);
            ldpair(o1,       v100, v101);
            ldpair(o1 + RX_, v110, v111);

            float c00 = v000 + (v001 - v000) * wx;
            float c01 = v010 + (v011 - v010) * wx;
            float c10 = v100 + (v101 - v100) * wx;
            float c11 = v110 + (v111 - v110) * wx;
            float c0 = c00 + (c01 - c00) * wy;
            float c1 = c10 + (c11 - c10) * wy;
            float res = c0 + (c1 - c0) * wz;

            bool do_store = in;
            if (!in) {
                int idx = atomicAdd(&qc[par], 1);
                if (idx < QCAP_) {
                    qd[par][idx] = f32x4{__int_as_float(s), gdx, gdy, gdz};
                } else {
                    res = gglobal(x, y, z, gdx, gdy, gdz);
                    do_store = true;
                }
            }
            if (do_store) __builtin_nontemporal_store(res, op + s);
        };

        // ---- compute k=0,1 (staging volley 1 in flight) ----
        process(zlo + zz,     s0,           cdx[0], cdy[0], cdz[0]);
        process(zlo + zz + 4, s0 + 4 * HW_, cdx[1], cdy[1], cdz[1]);

        // ---- commit volley 1 into bW; issue volley 2 ----
        COMMIT(sv0, sp0, sm0)
        COMMIT(sv1, sp1, sm1)
        COMMIT(sv2, sp2, sm2)
        COMMIT(sv3, sp3, sm3)
        COMMIT(sv4, sp4, sm4)
        ISSUE(5, sv0, sp0, sm0)
        ISSUE(6, sv1, sp1, sm1)
        ISSUE(7, sv2, sp2, sm2)
        ISSUE(8, sv3, sp3, sm3)
        ISSUE(9, sv4, sp4, sm4)

        // ---- compute k=2..4 (staging volley 2 in flight) ----
        process(zlo + zz + 8,  s0 + 8 * HW_,  cdx[2], cdy[2], cdz[2]);
        process(zlo + zz + 12, s0 + 12 * HW_, cdx[3], cdy[3], cdz[3]);
        process(zlo + zz + 16, s0 + 16 * HW_, cdx[4], cdy[4], cdz[4]);

        // ---- commit volley 2 ----
        COMMIT(sv0, sp0, sm0)
        COMMIT(sv1, sp1, sm1)
        COMMIT(sv2, sp2, sm2)
        COMMIT(sv3, sp3, sm3)
        COMMIT(sv4, sp4, sm4)
#undef ISSUE
#undef COMMIT

        __syncthreads();    // buf[t+1] complete; queue[par] pushes visible

        // ---- per-tile epilogue: exact-f32 global gathers for misses ----
        int n = min(qc[par], QCAP_);
        for (int i = tid; i < n; i += 1024) {
            f32x4 q = qd[par][i];
            int sq = __float_as_int(q.x);
            int zq = sq / HW_;
            int rq = sq - zq * HW_;
            int yq = rq / W_;
            int xq = rq - yq * W_;
            float ixq = fminf(fmaxf((float)xq + q.y, 0.f), (float)(W_ - 1));
            float iyq = fminf(fmaxf((float)yq + q.z, 0.f), (float)(H_ - 1));
            float izq = fminf(fmaxf((float)zq + q.w, 0.f), (float)(D_ - 1));
            int x0 = min((int)ixq, W_ - 2);
            int y0 = min((int)iyq, H_ - 2);
            int z0 = min((int)izq, D_ - 2);
            float wx = ixq - (float)x0;
            float wy = iyq - (float)y0;
            float wz = izq - (float)z0;
            const float* p = im + (z0 * HW_ + y0 * W_ + x0);
            f32x2 a = *(const f32x2*)(p);
            f32x2 c = *(const f32x2*)(p + W_);
            f32x2 e = *(const f32x2*)(p + HW_);
            f32x2 f = *(const f32x2*)(p + HW_ + W_);
            float c00 = a.x + (a.y - a.x) * wx;
            float c01 = c.x + (c.y - c.x) * wx;
            float c10 = e.x + (e.y - e.x) * wx;
            float c11 = f.x + (f.y - f.x) * wx;
            float c0 = c00 + (c01 - c00) * wy;
            float c1 = c10 + (c11 - c10) * wy;
            op[sq] = c0 + (c1 - c0) * wz;
        }
        if (tid == 0) qc[par ^ 1] = 0;
        __syncthreads();    // reset visible before next tile's pushes

        // ---- roll params to tile t+1 ----
        if (more) {
            zlo = nzlo; vz0 = nvz0; rx = nrx; ry = nry;
            im = nim; dp = ndp; op = nop;
            x = nx; y = nyv; s0 = ns0;
#pragma unroll
            for (int k = 0; k < 5; ++k) {
                cdz[k] = ndz[k]; cdy[k] = ndy[k]; cdx[k] = ndxr[k];
            }
        }
    }
}

extern "C" void kernel_launch(void* const* d_in, const int* in_sizes, int n_in,
                              void* d_out, int out_size, void* d_ws, size_t ws_size,
                              hipStream_t stream) {
    const float* img = (const float*)d_in[0];
    const float* ddf = (const float*)d_in[1];
    float*       out = (float*)d_out;

    warp3d_kernel<<<NBLK_, 1024, 0, stream>>>(img, ddf, out);
}

// Round 20
// 83.783 us; speedup vs baseline: 1.3717x; 1.3717x over previous
//
#include <hip/hip_runtime.h>

// 3D trilinear warp (grid_sample, align_corners=True, border padding).
// image: (B=2, 1, 160, 192, 192) f32 | ddf: (B,3,D,H,W) f32 (dz,dy,dx voxels)
//
// FINAL (= Round-18, measured best 83.8us): one-shot LDS window staged via
// async global_load_lds, split-phase, miss queue + global epilogue.
//  - Grid 6 x 24 x 8 x 2 = 2304 blocks = exactly 9/CU, 1024 threads.
//  - Window: 32 slices [zlo-4, zlo+28) of a 52x23 region (153 KB), direct
//    slot mapping. LDS dest pattern linear in chunk id (wave-uniform base +
//    lane*16, prefix-active guards) -> global_load_lds width=16 legal.
//  - Phase A: async-stage slices [zlo-4, zlo+12) -> barrier -> fire
//    phase-B global_load_lds (slots 16..31, disjoint from k0/k1 reads) ->
//    compute k=0,1 -> barrier (drains B) -> compute k=2..4 full window.
//  - Branchless LDS reads via single final-offset clamp; misses push
//    {s,dx,dy,dz} to LDS queue; epilogue gathers f32 from global (L2-hot).
//  - XCD-chunked bijective swizzle: concurrent xy-neighbor blocks share
//    halo lines in their XCD's L2 (persistence breaks this -- R19: 3x FETCH).
//
// History: 197 naive -> 166 batch+XCD -> 120 3D-tile -> 101 rolling-z ->
// 89 miss-queue -> 87.5 one-shot -> 85.3 split-phase -> 83.8 async-stage.
// Rejected: co-residency (x4 attempts), persistence (114.9), XOR swizzle,
// compiler batching. Residual: latency-bound, no pipe >32%.

typedef float f32x4 __attribute__((ext_vector_type(4)));
typedef float f32x2 __attribute__((ext_vector_type(2)));

constexpr int D_ = 160, H_ = 192, W_ = 192;
constexpr int HW_ = H_ * W_;
constexpr int N_  = D_ * HW_;

constexpr int TX_ = 32, TY_ = 8;
constexpr int XT_ = W_ / TX_;               // 6
constexpr int YT_ = H_ / TY_;               // 24
constexpr int ZH_ = 8;
constexpr int ZRUN_ = D_ / ZH_;             // 20
constexpr int NBLK_ = XT_ * YT_ * ZH_ * 2;  // 2304 = 9 * 256 exactly

constexpr int RX_ = 52, RY_ = 23, NZ_ = 32;
constexpr int SLICE_ = RX_ * RY_;           // 1196 floats (multiple of 4)
constexpr int CPS_ = SLICE_ / 4;            // 299 dwordx4 chunks per slice
constexpr int CPR_ = RX_ / 4;               // 13 chunks per row
constexpr int LIM_ = NZ_ * SLICE_ - RX_ - 2;// 38218: max safe base offset
constexpr int QCAP_ = 512;

__device__ __forceinline__ void gload_lds16(const float* src, float* dst) {
    __builtin_amdgcn_global_load_lds(
        (const __attribute__((address_space(1))) unsigned*)src,
        (__attribute__((address_space(3))) unsigned*)dst,
        16, 0, 0);
}

__global__ __launch_bounds__(1024) void warp3d_kernel(
    const float* __restrict__ img,
    const float* __restrict__ ddf,
    float* __restrict__ out)
{
    __shared__ float tile[NZ_ * SLICE_];    // 153,088 B
    __shared__ f32x4 qdat[QCAP_];           // 8,192 B
    __shared__ int   qcount;

    constexpr int CPX = NBLK_ / 8;          // 288
    int bid = blockIdx.x;
    int swz = (bid & 7) * CPX + (bid >> 3);

    int tx = swz % XT_;  int t1 = swz / XT_;
    int ty = t1 % YT_;   int t2 = t1 / YT_;
    int zh = t2 % ZH_;   int b  = t2 / ZH_;

    int zlo = zh * ZRUN_;
    int vz0 = zlo - 4;                      // virtual window origin (may be <0)
    int rx = min(max(tx * TX_ - 8, 0), W_ - RX_);   // always %4==0
    int ry = min(max(ty * TY_ - 7, 0), H_ - RY_);

    const float* im = img + (size_t)b * N_;
    const float* dp = ddf + (size_t)b * 3 * N_;
    float*       op = out + (size_t)b * N_;

    int tid = threadIdx.x;
    int xi = tid & 31;
    int yy = (tid >> 5) & 7;
    int zz = tid >> 8;                      // 0..3

    int x = tx * TX_ + xi;
    int y = ty * TY_ + yy;
    int s0 = ((zlo + zz) * H_ + y) * W_ + x;

    // ---- ddf loads for all 5 voxels (drain together with phase-A staging) --
    float ddz[5], ddy[5], ddxv[5];
#pragma unroll
    for (int k = 0; k < 5; ++k) {
        int s = s0 + k * 4 * HW_;
        ddz[k]  = __builtin_nontemporal_load(dp + s);
        ddy[k]  = __builtin_nontemporal_load(dp + N_ + s);
        ddxv[k] = __builtin_nontemporal_load(dp + 2 * N_ + s);
    }

    if (tid == 0) qcount = 0;

    // ---- phase A: async-stage slices [max(0,vz0), zlo+12) -> slots [.,16) --
    int pzA0 = max(0, vz0);
    int pcntA = (zlo + 12 - pzA0) * CPS_;
    int A0f   = (pzA0 - vz0) * SLICE_;
#pragma unroll
    for (int k = 0; k < 5; ++k) {
        int c = tid + (k << 10);
        if (c < pcntA) {                    // prefix-active within each wave
            int si  = c / CPS_;
            int rem = c - si * CPS_;
            int zs  = pzA0 + si;
            int row = rem / CPR_;
            int col = rem - row * CPR_;
            gload_lds16(im + (zs * H_ + ry + row) * W_ + rx + col * 4,
                        &tile[A0f + 4 * c]);
        }
    }
    __syncthreads();                        // drains vmcnt: window A ready

    // ---- phase B: fire-and-forget async-stage slices [zlo+12, zlo+28) ----
    // Dest slots 16..31 are disjoint from k0/k1's in-window reads (<=15);
    // concurrent garbage reads by miss voxels are discarded.
    {
        int zB0 = zlo + 12;
        int pcntB = (min(D_, zlo + 28) - zB0) * CPS_;
        int B0f = (zB0 - vz0) * SLICE_;     // 16 * SLICE_
#pragma unroll
        for (int k = 0; k < 5; ++k) {
            int c = tid + (k << 10);
            if (c < pcntB) {                // prefix-active within each wave
                int si  = c / CPS_;
                int rem = c - si * CPS_;
                int zs  = zB0 + si;
                int row = rem / CPR_;
                int col = rem - row * CPR_;
                gload_lds16(im + (zs * H_ + ry + row) * W_ + rx + col * 4,
                            &tile[B0f + 4 * c]);
            }
        }
    }

    // global gather (overflow + epilogue path)
    auto gglobal = [&](int vx, int vy, int vz,
                       float gdx, float gdy, float gdz) -> float {
        float ix = fminf(fmaxf((float)vx + gdx, 0.f), (float)(W_ - 1));
        float iy = fminf(fmaxf((float)vy + gdy, 0.f), (float)(H_ - 1));
        float iz = fminf(fmaxf((float)vz + gdz, 0.f), (float)(D_ - 1));
        int x0 = min((int)ix, W_ - 2);
        int y0 = min((int)iy, H_ - 2);
        int z0 = min((int)iz, D_ - 2);
        float wx = ix - (float)x0;
        float wy = iy - (float)y0;
        float wz = iz - (float)z0;
        const float* p = im + (z0 * HW_ + y0 * W_ + x0);
        f32x2 a = *(const f32x2*)(p);
        f32x2 c = *(const f32x2*)(p + W_);
        f32x2 e = *(const f32x2*)(p + HW_);
        f32x2 f = *(const f32x2*)(p + HW_ + W_);
        float c00 = a.x + (a.y - a.x) * wx;
        float c01 = c.x + (c.y - c.x) * wx;
        float c10 = e.x + (e.y - e.x) * wx;
        float c11 = f.x + (f.y - f.x) * wx;
        float c0 = c00 + (c01 - c00) * wy;
        float c1 = c10 + (c11 - c10) * wy;
        return c0 + (c1 - c0) * wz;
    };

    // one voxel: LDS window read (single final-offset clamp) + queue on miss
    auto process = [&](int z, int s, float gdx, float gdy, float gdz,
                       int uzTop) {
        float ix = fminf(fmaxf((float)x + gdx, 0.f), (float)(W_ - 1));
        float iy = fminf(fmaxf((float)y + gdy, 0.f), (float)(H_ - 1));
        float iz = fminf(fmaxf((float)z + gdz, 0.f), (float)(D_ - 1));

        int x0 = min((int)ix, W_ - 2);
        int y0 = min((int)iy, H_ - 2);
        int z0 = min((int)iz, D_ - 2);
        float wx = ix - (float)x0;
        float wy = iy - (float)y0;
        float wz = iz - (float)z0;

        int ux = x0 - rx, uy = y0 - ry, uz = z0 - vz0;
        bool in = ((unsigned)ux <= (unsigned)(RX_ - 2)) &
                  ((unsigned)uy <= (unsigned)(RY_ - 2)) &
                  ((unsigned)uz <= (unsigned)uzTop);

        int o0 = uz * SLICE_ + uy * RX_ + ux;   // raw; may be out of range
        o0 = min(max(o0, 0), LIM_);             // memory-safe (garbage on miss)
        int o1 = min(o0 + SLICE_, LIM_);

        float v000 = tile[o0];       float v001 = tile[o0 + 1];
        float v010 = tile[o0 + RX_]; float v011 = tile[o0 + RX_ + 1];
        float v100 = tile[o1];       float v101 = tile[o1 + 1];
        float v110 = tile[o1 + RX_]; float v111 = tile[o1 + RX_ + 1];

        float c00 = v000 + (v001 - v000) * wx;
        float c01 = v010 + (v011 - v010) * wx;
        float c10 = v100 + (v101 - v100) * wx;
        float c11 = v110 + (v111 - v110) * wx;
        float c0 = c00 + (c01 - c00) * wy;
        float c1 = c10 + (c11 - c10) * wy;
        float res = c0 + (c1 - c0) * wz;

        bool do_store = in;
        if (!in) {
            int idx = atomicAdd(&qcount, 1);
            if (idx < QCAP_) {
                qdat[idx] = f32x4{__int_as_float(s), gdx, gdy, gdz};
            } else {
                res = gglobal(x, y, z, gdx, gdy, gdz);
                do_store = true;
            }
        }
        if (do_store) __builtin_nontemporal_store(res, op + s);
    };

    // ---- compute k=0,1 against phase-A window (slots 0..15 -> uz<=14) ----
    process(zlo + zz,     s0,           ddxv[0], ddy[0], ddz[0], 14);
    process(zlo + zz + 4, s0 + 4 * HW_, ddxv[1], ddy[1], ddz[1], 14);

    __syncthreads();                        // drains phase-B loads: full window

    // ---- compute k=2..4 with the full window (uz<=30) ----
    process(zlo + zz + 8,  s0 + 8 * HW_,  ddxv[2], ddy[2], ddz[2], 30);
    process(zlo + zz + 12, s0 + 12 * HW_, ddxv[3], ddy[3], ddz[3], 30);
    process(zlo + zz + 16, s0 + 16 * HW_, ddxv[4], ddy[4], ddz[4], 30);

    __syncthreads();

    // ---- epilogue: resolve queued misses (ddf from queue, gathers L2-hot) --
    int n = min(qcount, QCAP_);
    for (int i = tid; i < n; i += 1024) {
        f32x4 q = qdat[i];
        int sq = __float_as_int(q.x);
        int zq = sq / HW_;
        int rq = sq - zq * HW_;
        int yq = rq / W_;
        int xq = rq - yq * W_;
        float res = gglobal(xq, yq, zq, q.y, q.z, q.w);
        op[sq] = res;
    }
}

extern "C" void kernel_launch(void* const* d_in, const int* in_sizes, int n_in,
                              void* d_out, int out_size, void* d_ws, size_t ws_size,
                              hipStream_t stream) {
    const float* img = (const float*)d_in[0];
    const float* ddf = (const float*)d_in[1];
    float*       out = (float*)d_out;

    warp3d_kernel<<<NBLK_, 1024, 0, stream>>>(img, ddf, out);
}